// Round 1
// baseline (871.121 us; speedup 1.0000x reference)
//
#include <hip/hip_runtime.h>
#include <hip/hip_bf16.h>
#include <cstddef>

#define N_NODES 100000
#define F_IN    512
#define HID     64
#define NCLS    40

__device__ __forceinline__ void atomAddF(float* p, float v) {
    // guaranteed global_atomic_add_f32 on gfx950 (device memory)
    unsafeAtomicAdd(p, v);
}

// ---------- degree / normalization ----------
__global__ void init_deg_kernel(float* __restrict__ deg, int n) {
    int i = blockIdx.x * blockDim.x + threadIdx.x;
    if (i < n) deg[i] = 1.0f;   // self-loop
}

__global__ void count_deg_kernel(const int* __restrict__ dst, float* __restrict__ deg, int E) {
    int e = blockIdx.x * blockDim.x + threadIdx.x;
    if (e < E) atomAddF(&deg[dst[e]], 1.0f);
}

__global__ void make_dinv_kernel(float* __restrict__ deg, int n) {
    int i = blockIdx.x * blockDim.x + threadIdx.x;
    if (i < n) deg[i] = rsqrtf(deg[i]);   // deg >= 1 always (self-loop)
}

// ---------- GEMM1: H1 = X (Mx512) @ W1 (512x64) ----------
#define BK 32
__global__ __launch_bounds__(256) void gemm1_kernel(const float* __restrict__ X,
                                                    const float* __restrict__ W,
                                                    float* __restrict__ H,
                                                    int M) {
    __shared__ float As[BK][68];   // transposed A tile: As[k][m], stride 68 (16B aligned, low conflict)
    __shared__ float Bs[BK][64];   // Bs[k][n]

    const int tid = threadIdx.x;
    const int tx = tid & 15;       // output col group (4 cols)
    const int ty = tid >> 4;       // output row group (4 rows)
    const int rowBase = blockIdx.x * 64;

    const int a_row = tid >> 3;    // 0..31
    const int a_q   = tid & 7;     // 0..7 (16B chunk within 32-wide k slab)
    const int b_row = tid >> 4;    // 0..15
    const int b_c4  = tid & 15;    // 0..15

    float acc[4][4] = {};

    for (int kt = 0; kt < F_IN; kt += BK) {
        // load A tile (64 rows x 32 k), transpose into LDS
        #pragma unroll
        for (int h = 0; h < 2; ++h) {
            int r = a_row + h * 32;
            int gr = rowBase + r;
            if (gr >= M) gr = M - 1;             // clamp; stores are guarded
            const float4 v = *reinterpret_cast<const float4*>(
                &X[(size_t)gr * F_IN + kt + a_q * 4]);
            As[a_q * 4 + 0][r] = v.x;
            As[a_q * 4 + 1][r] = v.y;
            As[a_q * 4 + 2][r] = v.z;
            As[a_q * 4 + 3][r] = v.w;
        }
        // load B tile (32 k x 64 n)
        #pragma unroll
        for (int h = 0; h < 2; ++h) {
            int kr = b_row + h * 16;
            const float4 v = *reinterpret_cast<const float4*>(
                &W[(size_t)(kt + kr) * 64 + b_c4 * 4]);
            *reinterpret_cast<float4*>(&Bs[kr][b_c4 * 4]) = v;
        }
        __syncthreads();

        #pragma unroll
        for (int k = 0; k < BK; ++k) {
            const float4 a = *reinterpret_cast<const float4*>(&As[k][ty * 4]);
            const float4 b = *reinterpret_cast<const float4*>(&Bs[k][tx * 4]);
            acc[0][0] += a.x * b.x; acc[0][1] += a.x * b.y; acc[0][2] += a.x * b.z; acc[0][3] += a.x * b.w;
            acc[1][0] += a.y * b.x; acc[1][1] += a.y * b.y; acc[1][2] += a.y * b.z; acc[1][3] += a.y * b.w;
            acc[2][0] += a.z * b.x; acc[2][1] += a.z * b.y; acc[2][2] += a.z * b.z; acc[2][3] += a.z * b.w;
            acc[3][0] += a.w * b.x; acc[3][1] += a.w * b.y; acc[3][2] += a.w * b.z; acc[3][3] += a.w * b.w;
        }
        __syncthreads();
    }

    #pragma unroll
    for (int i = 0; i < 4; ++i) {
        int gr = rowBase + ty * 4 + i;
        if (gr < M) {
            float4 v = make_float4(acc[i][0], acc[i][1], acc[i][2], acc[i][3]);
            *reinterpret_cast<float4*>(&H[(size_t)gr * HID + tx * 4]) = v;
        }
    }
}

// ---------- aggregation, width 64 ----------
__global__ void agg_init64_kernel(const float* __restrict__ h, const float* __restrict__ dinv,
                                  float* __restrict__ out, int M) {
    int idx = blockIdx.x * blockDim.x + threadIdx.x;
    if (idx < M * HID) {
        int n = idx >> 6;
        float di = dinv[n];
        out[idx] = h[idx] * di * di;   // self-loop contribution
    }
}

__global__ void agg_edges64_kernel(const float* __restrict__ h, const int* __restrict__ src,
                                   const int* __restrict__ dst, const float* __restrict__ dinv,
                                   float* __restrict__ out, int E) {
    const int j = threadIdx.x & 63;
    const int groupsPerBlock = blockDim.x >> 6;
    const int group = blockIdx.x * groupsPerBlock + (threadIdx.x >> 6);
    const int nGroups = gridDim.x * groupsPerBlock;
    for (int e = group; e < E; e += nGroups) {
        int s = src[e], d = dst[e];
        float norm = dinv[s] * dinv[d];
        float v = h[(size_t)s * HID + j] * norm;
        atomAddF(&out[(size_t)d * HID + j], v);
    }
}

// ---------- GEMM2: H2 = relu(AGG1 + b1) @ W2 (64x40) ----------
__global__ __launch_bounds__(256) void gemm2_kernel(const float* __restrict__ A,
                                                    const float* __restrict__ W,
                                                    const float* __restrict__ bias,
                                                    float* __restrict__ H2,
                                                    int M) {
    __shared__ float hs[32][68];
    __shared__ float ws[HID * NCLS];

    const int tid = threadIdx.x;
    const int rowBase = blockIdx.x * 32;

    for (int i = tid; i < HID * NCLS; i += 256) ws[i] = W[i];

    // load 32 rows, apply bias + relu
    #pragma unroll
    for (int p = 0; p < 2; ++p) {
        int i = p * 256 + tid;      // 0..511 -> 32 rows x 16 float4
        int r = i >> 4, c4 = i & 15;
        int gr = rowBase + r;
        float4 v;
        if (gr < M) {
            v = *reinterpret_cast<const float4*>(&A[(size_t)gr * HID + c4 * 4]);
        } else {
            v = make_float4(0.f, 0.f, 0.f, 0.f);
        }
        const float4 bb = *reinterpret_cast<const float4*>(&bias[c4 * 4]);
        v.x = fmaxf(v.x + bb.x, 0.f);
        v.y = fmaxf(v.y + bb.y, 0.f);
        v.z = fmaxf(v.z + bb.z, 0.f);
        v.w = fmaxf(v.w + bb.w, 0.f);
        *reinterpret_cast<float4*>(&hs[r][c4 * 4]) = v;
    }
    __syncthreads();

    #pragma unroll
    for (int p = 0; p < 5; ++p) {
        int o = p * 256 + tid;         // 0..1279 = 32 rows x 40 cols
        int r = o / NCLS, j = o % NCLS;
        float s = 0.f;
        #pragma unroll
        for (int k = 0; k < HID; ++k) s += hs[r][k] * ws[k * NCLS + j];
        int gr = rowBase + r;
        if (gr < M) H2[(size_t)gr * NCLS + j] = s;
    }
}

// ---------- aggregation, width 40 ----------
__global__ void agg_init40_kernel(const float* __restrict__ h, const float* __restrict__ dinv,
                                  float* __restrict__ out, int M) {
    int idx = blockIdx.x * blockDim.x + threadIdx.x;
    if (idx < M * NCLS) {
        int n = idx / NCLS;
        float di = dinv[n];
        out[idx] = h[idx] * di * di;
    }
}

__global__ void agg_edges40_kernel(const float* __restrict__ h, const int* __restrict__ src,
                                   const int* __restrict__ dst, const float* __restrict__ dinv,
                                   float* __restrict__ out, int E) {
    const long long total = (long long)E * NCLS;
    const long long stride = (long long)gridDim.x * blockDim.x;
    for (long long idx = (long long)blockIdx.x * blockDim.x + threadIdx.x; idx < total; idx += stride) {
        int e = (int)(idx / NCLS);
        int j = (int)(idx - (long long)e * NCLS);
        int s = src[e], d = dst[e];
        float norm = dinv[s] * dinv[d];
        atomAddF(&out[(size_t)d * NCLS + j], h[(size_t)s * NCLS + j] * norm);
    }
}

// ---------- bias + log_softmax (in place on d_out) ----------
__global__ void lsm_kernel(float* __restrict__ out, const float* __restrict__ b2, int M) {
    int n = blockIdx.x * blockDim.x + threadIdx.x;
    if (n >= M) return;
    float v[NCLS];
    float m = -1e30f;
    #pragma unroll
    for (int j = 0; j < NCLS; ++j) {
        v[j] = out[(size_t)n * NCLS + j] + b2[j];
        m = fmaxf(m, v[j]);
    }
    float s = 0.f;
    #pragma unroll
    for (int j = 0; j < NCLS; ++j) s += expf(v[j] - m);
    float l = logf(s);
    #pragma unroll
    for (int j = 0; j < NCLS; ++j) out[(size_t)n * NCLS + j] = v[j] - m - l;
}

extern "C" void kernel_launch(void* const* d_in, const int* in_sizes, int n_in,
                              void* d_out, int out_size, void* d_ws, size_t ws_size,
                              hipStream_t stream) {
    const float* x  = (const float*)d_in[0];
    const int*   ei = (const int*)d_in[1];
    const float* W1 = (const float*)d_in[2];
    const float* b1 = (const float*)d_in[3];
    const float* W2 = (const float*)d_in[4];
    const float* b2 = (const float*)d_in[5];
    float* out = (float*)d_out;

    const int M = N_NODES;
    const int E = in_sizes[1] / 2;
    const int* src = ei;
    const int* dst = ei + E;

    char* ws = (char*)d_ws;
    float* deg  = (float*)ws;                               // 400 KB (deg -> dinv in place)
    float* h1   = (float*)(ws + (1u << 20));                // 25.6 MB
    float* agg1 = (float*)(ws + (1u << 20) + (32u << 20));  // 25.6 MB
    float* h2   = h1;                                       // reuse: h1 dead after agg_edges64

    init_deg_kernel<<<(M + 255) / 256, 256, 0, stream>>>(deg, M);
    count_deg_kernel<<<(E + 255) / 256, 256, 0, stream>>>(dst, deg, E);
    make_dinv_kernel<<<(M + 255) / 256, 256, 0, stream>>>(deg, M);

    gemm1_kernel<<<(M + 63) / 64, 256, 0, stream>>>(x, W1, h1, M);

    agg_init64_kernel<<<(M * HID + 255) / 256, 256, 0, stream>>>(h1, deg, agg1, M);
    agg_edges64_kernel<<<4096, 256, 0, stream>>>(h1, src, dst, deg, agg1, E);

    gemm2_kernel<<<(M + 31) / 32, 256, 0, stream>>>(agg1, W2, b1, h2, M);

    agg_init40_kernel<<<(M * NCLS + 255) / 256, 256, 0, stream>>>(h2, deg, out, M);
    agg_edges40_kernel<<<4096, 256, 0, stream>>>(h2, src, dst, deg, out, E);

    lsm_kernel<<<(M + 255) / 256, 256, 0, stream>>>(out, b2, M);
}

// Round 3
// 479.920 us; speedup vs baseline: 1.8151x; 1.8151x over previous
//
#include <hip/hip_runtime.h>
#include <hip/hip_bf16.h>
#include <cstddef>

#define N_NODES 100000
#define F_IN    512
#define HID     64
#define NCLS    40

// ---------- utility ----------
__global__ void zero_kernel(int* __restrict__ p, int n) {
    int i = blockIdx.x * blockDim.x + threadIdx.x;
    if (i < n) p[i] = 0;
}

// ---------- degree / normalization ----------
__global__ void count_deg_kernel(const int* __restrict__ dst, int* __restrict__ cnt, int E) {
    int e = blockIdx.x * blockDim.x + threadIdx.x;
    if (e < E) atomicAdd(&cnt[dst[e]], 1);
}

__global__ void make_dinv_kernel(const int* __restrict__ cnt, float* __restrict__ dinv, int n) {
    int i = blockIdx.x * blockDim.x + threadIdx.x;
    if (i < n) dinv[i] = rsqrtf((float)(cnt[i] + 1));   // +1 self-loop
}

// ---------- exclusive scan (2-level) over degree counts ----------
#define SCAN_ELEMS 1024   // elements per block

__global__ __launch_bounds__(256) void scan_partial_kernel(const int* __restrict__ cnt,
                                                           int* __restrict__ part, int M) {
    __shared__ int sd[256];
    const int b = blockIdx.x, t = threadIdx.x;
    const int base = b * SCAN_ELEMS;
    int s = 0;
    for (int i = t; i < SCAN_ELEMS; i += 256) {
        int idx = base + i;
        s += (idx < M) ? cnt[idx] : 0;
    }
    sd[t] = s; __syncthreads();
    for (int d = 128; d > 0; d >>= 1) {
        if (t < d) sd[t] += sd[t + d];
        __syncthreads();
    }
    if (t == 0) part[b] = sd[0];
}

__global__ void scan_single_kernel(int* __restrict__ part, int n) {
    __shared__ int sd[128];
    int t = threadIdx.x;
    int v = (t < n) ? part[t] : 0;
    sd[t] = v; __syncthreads();
    for (int d = 1; d < 128; d <<= 1) {
        int u = (t >= d) ? sd[t - d] : 0;
        __syncthreads();
        sd[t] += u;
        __syncthreads();
    }
    if (t < n) part[t] = sd[t] - v;   // exclusive
}

// writes off[] and cursor[]; cursor may ALIAS cnt (each thread reads its own
// cnt range into registers before writing the same indices).
__global__ __launch_bounds__(256) void scan_final_kernel(const int* __restrict__ cnt,
                                                         const int* __restrict__ part,
                                                         int* __restrict__ off,
                                                         int* __restrict__ cursor, int M) {
    __shared__ int sd[256];
    const int b = blockIdx.x, t = threadIdx.x;
    const int base = b * SCAN_ELEMS + t * 4;
    int cs[4];
    #pragma unroll
    for (int i = 0; i < 4; ++i) cs[i] = (base + i < M) ? cnt[base + i] : 0;
    const int tot = cs[0] + cs[1] + cs[2] + cs[3];
    sd[t] = tot; __syncthreads();
    for (int d = 1; d < 256; d <<= 1) {
        int u = (t >= d) ? sd[t - d] : 0;
        __syncthreads();
        sd[t] += u;
        __syncthreads();
    }
    int exc = sd[t] - tot + part[b];
    int run = exc;
    #pragma unroll
    for (int i = 0; i < 4; ++i) {
        if (base + i < M) { off[base + i] = run; cursor[base + i] = run; }
        run += cs[i];
    }
    if (base < M && base + 4 >= M) off[M] = run;   // total (trailing cs are 0)
}

// ---------- CSR scatter: bucket edges by dst, store src only ----------
__global__ void scatter_csr_kernel(const int* __restrict__ src, const int* __restrict__ dst,
                                   int* __restrict__ cursor,
                                   int* __restrict__ csr_src, int E) {
    int e = blockIdx.x * blockDim.x + threadIdx.x;
    if (e < E) {
        int d = dst[e];
        int pos = atomicAdd(&cursor[d], 1);
        csr_src[pos] = src[e];
    }
}

// ---------- GEMM1: H1 = X (Mx512) @ W1 (512x64) ----------
#define BK 32
__global__ __launch_bounds__(256) void gemm1_kernel(const float* __restrict__ X,
                                                    const float* __restrict__ W,
                                                    float* __restrict__ H,
                                                    int M) {
    __shared__ float As[BK][68];
    __shared__ float Bs[BK][64];

    const int tid = threadIdx.x;
    const int tx = tid & 15;
    const int ty = tid >> 4;
    const int rowBase = blockIdx.x * 64;

    const int a_row = tid >> 3;
    const int a_q   = tid & 7;
    const int b_row = tid >> 4;
    const int b_c4  = tid & 15;

    float acc[4][4] = {};

    for (int kt = 0; kt < F_IN; kt += BK) {
        #pragma unroll
        for (int h = 0; h < 2; ++h) {
            int r = a_row + h * 32;
            int gr = rowBase + r;
            if (gr >= M) gr = M - 1;
            const float4 v = *reinterpret_cast<const float4*>(
                &X[(size_t)gr * F_IN + kt + a_q * 4]);
            As[a_q * 4 + 0][r] = v.x;
            As[a_q * 4 + 1][r] = v.y;
            As[a_q * 4 + 2][r] = v.z;
            As[a_q * 4 + 3][r] = v.w;
        }
        #pragma unroll
        for (int h = 0; h < 2; ++h) {
            int kr = b_row + h * 16;
            const float4 v = *reinterpret_cast<const float4*>(
                &W[(size_t)(kt + kr) * 64 + b_c4 * 4]);
            *reinterpret_cast<float4*>(&Bs[kr][b_c4 * 4]) = v;
        }
        __syncthreads();

        #pragma unroll
        for (int k = 0; k < BK; ++k) {
            const float4 a = *reinterpret_cast<const float4*>(&As[k][ty * 4]);
            const float4 b = *reinterpret_cast<const float4*>(&Bs[k][tx * 4]);
            acc[0][0] += a.x * b.x; acc[0][1] += a.x * b.y; acc[0][2] += a.x * b.z; acc[0][3] += a.x * b.w;
            acc[1][0] += a.y * b.x; acc[1][1] += a.y * b.y; acc[1][2] += a.y * b.z; acc[1][3] += a.y * b.w;
            acc[2][0] += a.z * b.x; acc[2][1] += a.z * b.y; acc[2][2] += a.z * b.z; acc[2][3] += a.z * b.w;
            acc[3][0] += a.w * b.x; acc[3][1] += a.w * b.y; acc[3][2] += a.w * b.z; acc[3][3] += a.w * b.w;
        }
        __syncthreads();
    }

    #pragma unroll
    for (int i = 0; i < 4; ++i) {
        int gr = rowBase + ty * 4 + i;
        if (gr < M) {
            float4 v = make_float4(acc[i][0], acc[i][1], acc[i][2], acc[i][3]);
            *reinterpret_cast<float4*>(&H[(size_t)gr * HID + tx * 4]) = v;
        }
    }
}

// ---------- gather-based aggregation (one wave per node, width 64) ----------
// out[n] = sum_{s in csr[off[n]..off[n+1])} h[s]*dinv[s]*dinv[n] + h[n]*dinv[n]^2
// RELU=true additionally: out = max(out + bias, 0)
template<bool RELU>
__global__ __launch_bounds__(256) void agg_gather_kernel(const float* __restrict__ h,
                                                         const int* __restrict__ off,
                                                         const int* __restrict__ csr_src,
                                                         const float* __restrict__ dinv,
                                                         const float* __restrict__ bias,
                                                         float* __restrict__ out, int M) {
    const int lane = threadIdx.x & 63;
    const int n = blockIdx.x * 4 + (threadIdx.x >> 6);
    if (n >= M) return;

    const float di = dinv[n];
    float acc = h[(size_t)n * HID + lane] * di * di;   // self-loop

    const int s0 = off[n], s1 = off[n + 1];
    for (int e = s0; e < s1; ) {
        int   s  = 0;
        float nm = 0.f;
        if (e + lane < s1) {
            s  = csr_src[e + lane];
            nm = dinv[s] * di;
        }
        const int cnt = min(64, s1 - e);
        int j = 0;
        for (; j + 4 <= cnt; j += 4) {
            int sa = __shfl(s, j);
            int sb = __shfl(s, j + 1);
            int sc = __shfl(s, j + 2);
            int sd = __shfl(s, j + 3);
            float na = __shfl(nm, j);
            float nb = __shfl(nm, j + 1);
            float nc = __shfl(nm, j + 2);
            float nd = __shfl(nm, j + 3);
            float va = h[(size_t)sa * HID + lane];
            float vb = h[(size_t)sb * HID + lane];
            float vc = h[(size_t)sc * HID + lane];
            float vd = h[(size_t)sd * HID + lane];
            acc = fmaf(va, na, acc);
            acc = fmaf(vb, nb, acc);
            acc = fmaf(vc, nc, acc);
            acc = fmaf(vd, nd, acc);
        }
        for (; j < cnt; ++j) {
            int sj = __shfl(s, j);
            float nj = __shfl(nm, j);
            acc = fmaf(h[(size_t)sj * HID + lane], nj, acc);
        }
        e += cnt;
    }

    if (RELU) acc = fmaxf(acc + bias[lane], 0.0f);
    out[(size_t)n * HID + lane] = acc;
}

// ---------- GEMM2 (64->40) + b2 + log_softmax, fused ----------
__global__ __launch_bounds__(256) void gemm2_lsm_kernel(const float* __restrict__ A,
                                                        const float* __restrict__ W,
                                                        const float* __restrict__ b2,
                                                        float* __restrict__ out, int M) {
    __shared__ float ws[HID * NCLS];     // 64x40
    __shared__ float hs[32][68];
    __shared__ float h2[32][NCLS];
    __shared__ float stats[32][2];

    const int tid = threadIdx.x;
    const int rowBase = blockIdx.x * 32;

    for (int i = tid; i < HID * NCLS; i += 256) ws[i] = W[i];

    #pragma unroll
    for (int p = 0; p < 2; ++p) {
        int i = p * 256 + tid;           // 32 rows x 16 float4
        int r = i >> 4, c4 = i & 15;
        int gr = rowBase + r;
        float4 v = make_float4(0.f, 0.f, 0.f, 0.f);
        if (gr < M) v = *reinterpret_cast<const float4*>(&A[(size_t)gr * HID + c4 * 4]);
        *reinterpret_cast<float4*>(&hs[r][c4 * 4]) = v;
    }
    __syncthreads();

    #pragma unroll
    for (int p = 0; p < 5; ++p) {
        int o = p * 256 + tid;           // 32 x 40 = 1280
        int r = o / NCLS, j = o - r * NCLS;
        float s = b2[j];
        #pragma unroll
        for (int k = 0; k < HID; ++k) s += hs[r][k] * ws[k * NCLS + j];
        h2[r][j] = s;
    }
    __syncthreads();

    if (tid < 32) {
        float m = -1e30f;
        #pragma unroll
        for (int j = 0; j < NCLS; ++j) m = fmaxf(m, h2[tid][j]);
        float s = 0.f;
        #pragma unroll
        for (int j = 0; j < NCLS; ++j) s += expf(h2[tid][j] - m);
        stats[tid][0] = m;
        stats[tid][1] = logf(s);
    }
    __syncthreads();

    #pragma unroll
    for (int p = 0; p < 5; ++p) {
        int o = p * 256 + tid;
        int r = o / NCLS, j = o - r * NCLS;
        int gr = rowBase + r;
        if (gr < M) out[(size_t)gr * NCLS + j] = h2[r][j] - stats[r][0] - stats[r][1];
    }
}

extern "C" void kernel_launch(void* const* d_in, const int* in_sizes, int n_in,
                              void* d_out, int out_size, void* d_ws, size_t ws_size,
                              hipStream_t stream) {
    const float* x  = (const float*)d_in[0];
    const int*   ei = (const int*)d_in[1];
    const float* W1 = (const float*)d_in[2];
    const float* b1 = (const float*)d_in[3];
    const float* W2 = (const float*)d_in[4];
    const float* b2 = (const float*)d_in[5];
    float* out = (float*)d_out;

    const int M = N_NODES;
    const int E = in_sizes[1] / 2;
    const int* src = ei;
    const int* dst = ei + E;

    // ---- workspace layout (peak 58.84 MB < 57.4 MiB proven-safe bound) ----
    char* ws = (char*)d_ws;
    int*   cnt     = (int*)  (ws + 0);                 // 400 KB  (reused as cursor)
    float* dinv    = (float*)(ws + 409600);            // 400 KB
    int*   off     = (int*)  (ws + 819200);            // 400 KB + 4
    int*   part    = (int*)  (ws + 1232896);           // 392 B
    int*   csr_src = (int*)  (ws + 1236992);           // 6.4 MB  -> ends 7,636,992
    float* h1      = (float*)(ws + 7639040);           // 25.6 MB -> ends 33,239,040
    float* z       = (float*)(ws + 33239040);          // 25.6 MB -> ends 58,839,040
    int*   cursor  = cnt;                              // alias: cnt dead after scan_final
    float* agg2    = h1;                               // alias: h1 dead after first agg

    const int nPart = (M + SCAN_ELEMS - 1) / SCAN_ELEMS;  // 98

    zero_kernel<<<(M + 255) / 256, 256, 0, stream>>>(cnt, M);
    count_deg_kernel<<<(E + 255) / 256, 256, 0, stream>>>(dst, cnt, E);
    make_dinv_kernel<<<(M + 255) / 256, 256, 0, stream>>>(cnt, dinv, M);

    scan_partial_kernel<<<nPart, 256, 0, stream>>>(cnt, part, M);
    scan_single_kernel<<<1, 128, 0, stream>>>(part, nPart);
    scan_final_kernel<<<nPart, 256, 0, stream>>>(cnt, part, off, cursor, M);
    scatter_csr_kernel<<<(E + 255) / 256, 256, 0, stream>>>(src, dst, cursor, csr_src, E);

    gemm1_kernel<<<(M + 63) / 64, 256, 0, stream>>>(x, W1, h1, M);

    agg_gather_kernel<true><<<(M + 3) / 4, 256, 0, stream>>>(h1, off, csr_src, dinv, b1, z, M);
    agg_gather_kernel<false><<<(M + 3) / 4, 256, 0, stream>>>(z, off, csr_src, dinv, nullptr, agg2, M);

    gemm2_lsm_kernel<<<(M + 31) / 32, 256, 0, stream>>>(agg2, W2, b2, out, M);
}